// Round 1
// baseline (460.543 us; speedup 1.0000x reference)
//
#include <hip/hip_runtime.h>

#define B_SZ 32768
#define I_SZ 256
#define H_SZ 512
#define K_SZ 768   // I + H
#define NG   2048  // 4*H

typedef _Float16 half8 __attribute__((ext_vector_type(8)));
typedef _Float16 half4v __attribute__((ext_vector_type(4)));
typedef float f32x4 __attribute__((ext_vector_type(4)));

__device__ __forceinline__ float sigf(float x) {
  // 1/(1+exp(-x)); exp via exp2. Saturates correctly at +-inf.
  return __builtin_amdgcn_rcpf(1.0f + __builtin_amdgcn_exp2f(-1.44269504089f * x));
}
__device__ __forceinline__ float tanh_fast(float x) {
  // tanh(x) = 1 - 2/(1+exp(2x)); robust for large |x| (exp2->inf => 1, ->0 => -1)
  return 1.0f - 2.0f * __builtin_amdgcn_rcpf(1.0f + __builtin_amdgcn_exp2f(2.88539008178f * x));
}

__device__ __forceinline__ void gl2lds16(const void* g, void* l) {
  __builtin_amdgcn_global_load_lds(
      (const __attribute__((address_space(1))) void*)g,
      (__attribute__((address_space(3))) void*)l, 16, 0, 0);
}

// ---------------- pre-pass: cast fp32 -> f16, pack [x|h] and [Wx|Wh] ----------------
__global__ void __launch_bounds__(256) cast_pack_A(const float* __restrict__ x,
                                                   const float* __restrict__ h,
                                                   _Float16* __restrict__ Aw) {
  int i = blockIdx.x * 256 + threadIdx.x;
  int e = i * 4;                     // element index in [0, B*768)
  int b = e / K_SZ;
  int col = e - b * K_SZ;
  float4 v;
  if (col < I_SZ) v = *(const float4*)(x + (size_t)b * I_SZ + col);
  else            v = *(const float4*)(h + (size_t)b * H_SZ + (col - I_SZ));
  half4v o = {(_Float16)v.x, (_Float16)v.y, (_Float16)v.z, (_Float16)v.w};
  *(half4v*)(Aw + e) = o;
}

__global__ void __launch_bounds__(256) cast_pack_W(const float* __restrict__ Wx,
                                                   const float* __restrict__ Wh,
                                                   _Float16* __restrict__ Ww) {
  int i = blockIdx.x * 256 + threadIdx.x;
  int e = i * 4;                     // element index in [0, 2048*768)
  int r = e / K_SZ;
  int col = e - r * K_SZ;
  float4 v;
  if (col < I_SZ) v = *(const float4*)(Wx + (size_t)r * I_SZ + col);
  else            v = *(const float4*)(Wh + (size_t)r * H_SZ + (col - I_SZ));
  half4v o = {(_Float16)v.x, (_Float16)v.y, (_Float16)v.z, (_Float16)v.w};
  *(half4v*)(Ww + e) = o;
}

__global__ void __launch_bounds__(256) bias_sum(const float* __restrict__ bx,
                                                const float* __restrict__ bh,
                                                float* __restrict__ bs) {
  int i = blockIdx.x * 256 + threadIdx.x;
  bs[i] = bx[i] + bh[i];
}

// ---------------- main fused GEMM + LSTM epilogue ----------------
// Block tile: 128 rows (batch) x 128 cols. Tile col c -> gate g=c&3, j=j0+(c>>2)
// (32 j-values per block, all 4 gates interleaved so the epilogue has them adjacent).
// 4 waves in 2x2; each wave 64x64 via 4x4 grid of 16x16x32 f16 MFMA. BK=64.
__global__ void __launch_bounds__(256) lstm_gemm(const _Float16* __restrict__ Aw,
                                                 const _Float16* __restrict__ Ww,
                                                 const float* __restrict__ bs,
                                                 const float* __restrict__ cIn,
                                                 float* __restrict__ outc,
                                                 float* __restrict__ outh) {
  __shared__ __align__(16) char smem[32768];
  _Float16* As = (_Float16*)smem;             // [128][64] row-major (row=batch row)
  _Float16* Ws = (_Float16*)(smem + 16384);   // [128][64] (row=tile col, K contiguous)

  const int t = threadIdx.x;
  const int lane = t & 63;
  const int wave = t >> 6;
  const int wr = wave >> 1, wc = wave & 1;
  const int l15 = lane & 15, l4 = lane >> 4;

  const int bid = blockIdx.x;
  const int nb = bid & 15, mb = bid >> 4;   // consecutive blocks share the A panel (L2)
  const int j0 = nb * 32;
  const int m0 = mb * 128;

  // staging: 4 rounds each for A and W; one round = 256 threads x 16B = 4KB (8 rows)
  const int rA = t >> 3;            // 0..31
  const int colb = (t & 7) * 8;     // f16 col within BK
  const size_t aBase = (size_t)(m0 + rA) * K_SZ + colb;
  // tile col c = q*32 + rA: gate g = rA&3 (q*32 % 4 == 0), j index = q*8 + (rA>>2)
  const size_t wBase = (size_t)((rA & 3) * H_SZ + j0 + (rA >> 2)) * K_SZ + colb;
  char* ldsA = smem + t * 16;           // wave-uniform base + lane*16 (required pattern)
  char* ldsW = smem + 16384 + t * 16;

  // init accumulators with bias (all 4 rows of a C-reg share one column)
  f32x4 acc[4][4];
#pragma unroll
  for (int ni = 0; ni < 4; ++ni) {
    int tcol = wc * 64 + ni * 16 + l15;
    int gcol = (tcol & 3) * H_SZ + j0 + (tcol >> 2);
    float b = bs[gcol];
    f32x4 v = {b, b, b, b};
#pragma unroll
    for (int mi = 0; mi < 4; ++mi) acc[mi][ni] = v;
  }

  for (int kb = 0; kb < K_SZ / 64; ++kb) {
    const int k0 = kb * 64;
#pragma unroll
    for (int q = 0; q < 4; ++q) {
      gl2lds16(Aw + aBase + (size_t)q * 32 * K_SZ + k0, ldsA + q * 4096);
      gl2lds16(Ww + wBase + (size_t)q * 8 * K_SZ + k0, ldsW + q * 4096);
    }
    __syncthreads();   // compiler emits vmcnt(0) drain before barrier
#pragma unroll
    for (int ks = 0; ks < 2; ++ks) {
      half8 af[4], wf[4];
#pragma unroll
      for (int mi = 0; mi < 4; ++mi)
        af[mi] = *(const half8*)(As + (wr * 64 + mi * 16 + l15) * 64 + ks * 32 + l4 * 8);
#pragma unroll
      for (int ni = 0; ni < 4; ++ni)
        wf[ni] = *(const half8*)(Ws + (wc * 64 + ni * 16 + l15) * 64 + ks * 32 + l4 * 8);
#pragma unroll
      for (int mi = 0; mi < 4; ++mi)
#pragma unroll
        for (int ni = 0; ni < 4; ++ni)
          acc[mi][ni] = __builtin_amdgcn_mfma_f32_16x16x32_f16(af[mi], wf[ni], acc[mi][ni], 0, 0, 0);
    }
    __syncthreads();   // protect LDS before next stage overwrites
  }

  // ---- epilogue: per-wave LDS transpose so each lane gets (gi,gf,go,gc) contiguous ----
  // wave-private 8KB region (last barrier above guarantees staging reads are done)
  float* T = (float*)(smem + wave * 8192);  // used as [16][68] floats (stride 68: 2-way max)
#pragma unroll
  for (int mi = 0; mi < 4; ++mi) {
#pragma unroll
    for (int ni = 0; ni < 4; ++ni)
#pragma unroll
      for (int r = 0; r < 4; ++r)
        T[(l4 * 4 + r) * 68 + ni * 16 + l15] = acc[mi][ni][r];
    // lane -> j_local = l15, rows rloc = orow*4 + l4 (16 rows of this mi-slab)
#pragma unroll
    for (int orow = 0; orow < 4; ++orow) {
      int rloc = orow * 4 + l4;
      f32x4 gv = *(const f32x4*)(T + rloc * 68 + l15 * 4);  // g0..g3 of (row, j)
      int rowg = m0 + wr * 64 + mi * 16 + rloc;
      int jg = j0 + wc * 16 + l15;
      size_t off = (size_t)rowg * H_SZ + jg;
      float cv = cIn[off];
      float it = sigf(gv[0]);
      float ft = sigf(gv[1]);
      float ot = sigf(gv[2]);
      float tc = tanh_fast(gv[3]);
      float ct = ft * cv + it * tc;
      float ht = ot * tanh_fast(ct);
      outc[off] = ct;
      outh[off] = ht;
    }
  }
}

// ---------------- fallback (only if d_ws is too small): plain fp32, correct but slow ----------------
__global__ void __launch_bounds__(256) lstm_naive(const float* __restrict__ x,
                                                  const float* __restrict__ h,
                                                  const float* __restrict__ c,
                                                  const float* __restrict__ Wx,
                                                  const float* __restrict__ bx,
                                                  const float* __restrict__ Wh,
                                                  const float* __restrict__ bh,
                                                  float* __restrict__ outc,
                                                  float* __restrict__ outh) {
  int idx = blockIdx.x * 256 + threadIdx.x;
  int b = idx >> 9, j = idx & 511;
  float gi = bx[j] + bh[j];
  float gf = bx[H_SZ + j] + bh[H_SZ + j];
  float go = bx[2 * H_SZ + j] + bh[2 * H_SZ + j];
  float gc = bx[3 * H_SZ + j] + bh[3 * H_SZ + j];
  const float* xr = x + (size_t)b * I_SZ;
  for (int k = 0; k < I_SZ; ++k) {
    float xv = xr[k];
    gi += xv * Wx[(size_t)j * I_SZ + k];
    gf += xv * Wx[(size_t)(H_SZ + j) * I_SZ + k];
    go += xv * Wx[(size_t)(2 * H_SZ + j) * I_SZ + k];
    gc += xv * Wx[(size_t)(3 * H_SZ + j) * I_SZ + k];
  }
  const float* hr = h + (size_t)b * H_SZ;
  for (int k = 0; k < H_SZ; ++k) {
    float hv = hr[k];
    gi += hv * Wh[(size_t)j * H_SZ + k];
    gf += hv * Wh[(size_t)(H_SZ + j) * H_SZ + k];
    go += hv * Wh[(size_t)(2 * H_SZ + j) * H_SZ + k];
    gc += hv * Wh[(size_t)(3 * H_SZ + j) * H_SZ + k];
  }
  float it = sigf(gi), ft = sigf(gf), ot = sigf(go), tc = tanh_fast(gc);
  float ct = ft * c[idx] + it * tc;
  outc[idx] = ct;
  outh[idx] = ot * tanh_fast(ct);
}

extern "C" void kernel_launch(void* const* d_in, const int* in_sizes, int n_in,
                              void* d_out, int out_size, void* d_ws, size_t ws_size,
                              hipStream_t stream) {
  const float* x  = (const float*)d_in[0];
  const float* h  = (const float*)d_in[1];
  const float* c  = (const float*)d_in[2];
  const float* Wx = (const float*)d_in[3];
  const float* bx = (const float*)d_in[4];
  const float* Wh = (const float*)d_in[5];
  const float* bh = (const float*)d_in[6];
  float* outc = (float*)d_out;
  float* outh = outc + (size_t)B_SZ * H_SZ;

  const size_t szA = (size_t)B_SZ * K_SZ * sizeof(_Float16);  // 50,331,648
  const size_t szW = (size_t)NG * K_SZ * sizeof(_Float16);    //  3,145,728
  const size_t need = szA + szW + (size_t)NG * sizeof(float);

  if (ws_size < need) {
    lstm_naive<<<(B_SZ * H_SZ) / 256, 256, 0, stream>>>(x, h, c, Wx, bx, Wh, bh, outc, outh);
    return;
  }

  _Float16* Aw = (_Float16*)d_ws;
  _Float16* Ww = (_Float16*)((char*)d_ws + szA);
  float* bs = (float*)((char*)d_ws + szA + szW);

  cast_pack_A<<<(B_SZ * K_SZ / 4) / 256, 256, 0, stream>>>(x, h, Aw);
  cast_pack_W<<<(NG * K_SZ / 4) / 256, 256, 0, stream>>>(Wx, Wh, Ww);
  bias_sum<<<NG / 256, 256, 0, stream>>>(bx, bh, bs);
  lstm_gemm<<<(B_SZ / 128) * (H_SZ / 32), 256, 0, stream>>>(Aw, Ww, bs, c, outc, outh);
}

// Round 2
// 420.066 us; speedup vs baseline: 1.0964x; 1.0964x over previous
//
#include <hip/hip_runtime.h>

#define B_SZ 32768
#define I_SZ 256
#define H_SZ 512
#define K_SZ 768   // I + H
#define NG   2048  // 4*H

typedef _Float16 half8 __attribute__((ext_vector_type(8)));
typedef _Float16 half4v __attribute__((ext_vector_type(4)));
typedef float f32x4 __attribute__((ext_vector_type(4)));

__device__ __forceinline__ float sigf(float x) {
  return __builtin_amdgcn_rcpf(1.0f + __builtin_amdgcn_exp2f(-1.44269504089f * x));
}
__device__ __forceinline__ float tanh_fast(float x) {
  return 1.0f - 2.0f * __builtin_amdgcn_rcpf(1.0f + __builtin_amdgcn_exp2f(2.88539008178f * x));
}

__device__ __forceinline__ void gl2lds16(const void* g, void* l) {
  __builtin_amdgcn_global_load_lds(
      (const __attribute__((address_space(1))) void*)g,
      (__attribute__((address_space(3))) void*)l, 16, 0, 0);
}

// ---------------- fused pre-pass: cast fp32 -> f16 pack [x|h], [Wx|Wh], bias sum ----
// blockIdx < B_SZ        : pack one row of A  (x cols 0..255, h cols 256..767)
// blockIdx < B_SZ+NG     : pack one row of W  (Wx / Wh)
// blockIdx == B_SZ+NG    : bias
// 192 threads (3 waves): t<64 -> first segment (256 cols), t>=64 -> second (512 cols).
__global__ void __launch_bounds__(192) prepass(const float* __restrict__ x,
                                               const float* __restrict__ h,
                                               const float* __restrict__ Wx,
                                               const float* __restrict__ Wh,
                                               const float* __restrict__ bx,
                                               const float* __restrict__ bh,
                                               _Float16* __restrict__ Aw,
                                               _Float16* __restrict__ Ww,
                                               float* __restrict__ bs) {
  const int t = threadIdx.x;
  const int bid = blockIdx.x;
  if (bid < B_SZ) {
    const int r = bid;
    float4 v;
    int col;
    if (t < 64) { col = t * 4;          v = *(const float4*)(x + (size_t)r * I_SZ + col); }
    else        { col = 256 + (t - 64) * 4; v = *(const float4*)(h + (size_t)r * H_SZ + (col - 256)); }
    half4v o = {(_Float16)v.x, (_Float16)v.y, (_Float16)v.z, (_Float16)v.w};
    *(half4v*)(Aw + (size_t)r * K_SZ + col) = o;
  } else if (bid < B_SZ + NG) {
    const int r = bid - B_SZ;
    float4 v;
    int col;
    if (t < 64) { col = t * 4;          v = *(const float4*)(Wx + (size_t)r * I_SZ + col); }
    else        { col = 256 + (t - 64) * 4; v = *(const float4*)(Wh + (size_t)r * H_SZ + (col - 256)); }
    half4v o = {(_Float16)v.x, (_Float16)v.y, (_Float16)v.z, (_Float16)v.w};
    *(half4v*)(Ww + (size_t)r * K_SZ + col) = o;
  } else {
    for (int j = t; j < NG; j += 192) bs[j] = bx[j] + bh[j];
  }
}

// ---------------- main fused GEMM + LSTM epilogue ----------------
// Block tile: 128 rows (batch) x 128 cols. Tile col c -> gate g=c&3, j=j0+(c>>2).
// 4 waves in 2x2; each wave 64x64 via 4x4 grid of 16x16x32 f16 MFMA. BK=64.
// LDS XOR swizzle: LDS[row][chunk] holds global chunk (chunk ^ (row&7)); kills the
// 16-way ds_read_b128 bank conflict (row stride = 128B = full bank wrap).
__global__ void __launch_bounds__(256) lstm_gemm(const _Float16* __restrict__ Aw,
                                                 const _Float16* __restrict__ Ww,
                                                 const float* __restrict__ bs,
                                                 const float* __restrict__ cIn,
                                                 float* __restrict__ outc,
                                                 float* __restrict__ outh) {
  __shared__ __align__(16) char smem[32768];
  _Float16* As = (_Float16*)smem;             // [128][64], swizzled chunks
  _Float16* Ws = (_Float16*)(smem + 16384);   // [128][64], swizzled chunks

  const int t = threadIdx.x;
  const int lane = t & 63;
  const int wave = t >> 6;
  const int wr = wave >> 1, wc = wave & 1;
  const int l15 = lane & 15, l4 = lane >> 4;
  const int sw = l15 & 7;                     // read-side XOR key (row&7 == l15&7)

  const int bid = blockIdx.x;
  const int nb = bid & 15, mb = bid >> 4;
  const int j0 = nb * 32;
  const int m0 = mb * 128;

  // staging: thread t -> row rA = t>>3 (within 32-row group), chunk ct = t&7.
  // source chunk = ct ^ (rA&7)  (q*32 and q*8 are both ≡0 mod 8, so key uniform in q)
  const int rA = t >> 3;
  const int colb = ((t & 7) ^ (rA & 7)) * 8;  // f16 col within BK slice
  const size_t aBase = (size_t)(m0 + rA) * K_SZ + colb;
  const size_t wBase = (size_t)((rA & 3) * H_SZ + j0 + (rA >> 2)) * K_SZ + colb;
  char* ldsA = smem + t * 16;
  char* ldsW = smem + 16384 + t * 16;

  // init accumulators with bias
  f32x4 acc[4][4];
#pragma unroll
  for (int ni = 0; ni < 4; ++ni) {
    int tcol = wc * 64 + ni * 16 + l15;
    int gcol = (tcol & 3) * H_SZ + j0 + (tcol >> 2);
    float b = bs[gcol];
    f32x4 v = {b, b, b, b};
#pragma unroll
    for (int mi = 0; mi < 4; ++mi) acc[mi][ni] = v;
  }

  for (int kb = 0; kb < K_SZ / 64; ++kb) {
    const int k0 = kb * 64;
#pragma unroll
    for (int q = 0; q < 4; ++q) {
      gl2lds16(Aw + aBase + (size_t)q * 32 * K_SZ + k0, ldsA + q * 4096);
      gl2lds16(Ww + wBase + (size_t)q * 8 * K_SZ + k0, ldsW + q * 4096);
    }
    __syncthreads();
#pragma unroll
    for (int ks = 0; ks < 2; ++ks) {
      half8 af[4], wf[4];
#pragma unroll
      for (int mi = 0; mi < 4; ++mi)
        af[mi] = *(const half8*)(As + (wr * 64 + mi * 16 + l15) * 64 + (((ks * 4 + l4) ^ sw) * 8));
#pragma unroll
      for (int ni = 0; ni < 4; ++ni)
        wf[ni] = *(const half8*)(Ws + (wc * 64 + ni * 16 + l15) * 64 + (((ks * 4 + l4) ^ sw) * 8));
#pragma unroll
      for (int mi = 0; mi < 4; ++mi)
#pragma unroll
        for (int ni = 0; ni < 4; ++ni)
          acc[mi][ni] = __builtin_amdgcn_mfma_f32_16x16x32_f16(af[mi], wf[ni], acc[mi][ni], 0, 0, 0);
    }
    __syncthreads();
  }

  // ---- epilogue: per-wave LDS transpose (stride 68 floats: max 2-way = free) ----
  float* T = (float*)(smem + wave * 8192);
#pragma unroll
  for (int mi = 0; mi < 4; ++mi) {
#pragma unroll
    for (int ni = 0; ni < 4; ++ni)
#pragma unroll
      for (int r = 0; r < 4; ++r)
        T[(l4 * 4 + r) * 68 + ni * 16 + l15] = acc[mi][ni][r];
#pragma unroll
    for (int orow = 0; orow < 4; ++orow) {
      int rloc = orow * 4 + l4;
      f32x4 gv = *(const f32x4*)(T + rloc * 68 + l15 * 4);
      int rowg = m0 + wr * 64 + mi * 16 + rloc;
      int jg = j0 + wc * 16 + l15;
      size_t off = (size_t)rowg * H_SZ + jg;
      float cv = cIn[off];
      float it = sigf(gv[0]);
      float ft = sigf(gv[1]);
      float ot = sigf(gv[2]);
      float tc = tanh_fast(gv[3]);
      float ct = ft * cv + it * tc;
      float ht = ot * tanh_fast(ct);
      outc[off] = ct;
      outh[off] = ht;
    }
  }
}

// ---------------- fallback (ws too small): plain fp32 ----------------
__global__ void __launch_bounds__(256) lstm_naive(const float* __restrict__ x,
                                                  const float* __restrict__ h,
                                                  const float* __restrict__ c,
                                                  const float* __restrict__ Wx,
                                                  const float* __restrict__ bx,
                                                  const float* __restrict__ Wh,
                                                  const float* __restrict__ bh,
                                                  float* __restrict__ outc,
                                                  float* __restrict__ outh) {
  int idx = blockIdx.x * 256 + threadIdx.x;
  int b = idx >> 9, j = idx & 511;
  float gi = bx[j] + bh[j];
  float gf = bx[H_SZ + j] + bh[H_SZ + j];
  float go = bx[2 * H_SZ + j] + bh[2 * H_SZ + j];
  float gc = bx[3 * H_SZ + j] + bh[3 * H_SZ + j];
  const float* xr = x + (size_t)b * I_SZ;
  for (int k = 0; k < I_SZ; ++k) {
    float xv = xr[k];
    gi += xv * Wx[(size_t)j * I_SZ + k];
    gf += xv * Wx[(size_t)(H_SZ + j) * I_SZ + k];
    go += xv * Wx[(size_t)(2 * H_SZ + j) * I_SZ + k];
    gc += xv * Wx[(size_t)(3 * H_SZ + j) * I_SZ + k];
  }
  const float* hr = h + (size_t)b * H_SZ;
  for (int k = 0; k < H_SZ; ++k) {
    float hv = hr[k];
    gi += hv * Wh[(size_t)j * H_SZ + k];
    gf += hv * Wh[(size_t)(H_SZ + j) * H_SZ + k];
    go += hv * Wh[(size_t)(2 * H_SZ + j) * H_SZ + k];
    gc += hv * Wh[(size_t)(3 * H_SZ + j) * H_SZ + k];
  }
  float it = sigf(gi), ft = sigf(gf), ot = sigf(go), tc = tanh_fast(gc);
  float ct = ft * c[idx] + it * tc;
  outc[idx] = ct;
  outh[idx] = ot * tanh_fast(ct);
}

extern "C" void kernel_launch(void* const* d_in, const int* in_sizes, int n_in,
                              void* d_out, int out_size, void* d_ws, size_t ws_size,
                              hipStream_t stream) {
  const float* x  = (const float*)d_in[0];
  const float* h  = (const float*)d_in[1];
  const float* c  = (const float*)d_in[2];
  const float* Wx = (const float*)d_in[3];
  const float* bx = (const float*)d_in[4];
  const float* Wh = (const float*)d_in[5];
  const float* bh = (const float*)d_in[6];
  float* outc = (float*)d_out;
  float* outh = outc + (size_t)B_SZ * H_SZ;

  const size_t szA = (size_t)B_SZ * K_SZ * sizeof(_Float16);
  const size_t szW = (size_t)NG * K_SZ * sizeof(_Float16);
  const size_t need = szA + szW + (size_t)NG * sizeof(float);

  if (ws_size < need) {
    lstm_naive<<<(B_SZ * H_SZ) / 256, 256, 0, stream>>>(x, h, c, Wx, bx, Wh, bh, outc, outh);
    return;
  }

  _Float16* Aw = (_Float16*)d_ws;
  _Float16* Ww = (_Float16*)((char*)d_ws + szA);
  float* bs = (float*)((char*)d_ws + szA + szW);

  prepass<<<B_SZ + NG + 1, 192, 0, stream>>>(x, h, Wx, Wh, bx, bh, Aw, Ww, bs);
  lstm_gemm<<<(B_SZ / 128) * (NG / 128), 256, 0, stream>>>(Aw, Ww, bs, c, outc, outh);
}

// Round 3
// 383.246 us; speedup vs baseline: 1.2017x; 1.0961x over previous
//
#include <hip/hip_runtime.h>

#define B_SZ 32768
#define I_SZ 256
#define H_SZ 512
#define K_SZ 768   // I + H
#define NG   2048  // 4*H

typedef _Float16 half8 __attribute__((ext_vector_type(8)));
typedef _Float16 half4v __attribute__((ext_vector_type(4)));
typedef float f32x4 __attribute__((ext_vector_type(4)));

__device__ __forceinline__ float sigf(float x) {
  return __builtin_amdgcn_rcpf(1.0f + __builtin_amdgcn_exp2f(-1.44269504089f * x));
}
__device__ __forceinline__ float tanh_fast(float x) {
  return 1.0f - 2.0f * __builtin_amdgcn_rcpf(1.0f + __builtin_amdgcn_exp2f(2.88539008178f * x));
}

__device__ __forceinline__ void gl2lds16(const void* g, void* l) {
  __builtin_amdgcn_global_load_lds(
      (const __attribute__((address_space(1))) void*)g,
      (__attribute__((address_space(3))) void*)l, 16, 0, 0);
}

// ---------------- fused pre-pass ----------------
// blockIdx < B_SZ      : pack one row of A (f16 row-major [x|h])
// blockIdx < B_SZ+NG   : pack one row of W into MFMA-FRAGMENT order:
//     f = (((nb*2+wc)*12 + kb)*2 + ks)*4 + ni ; within f-block: lane(l4*16+l15)*8 + e
//     (lane l15 = tile-col%16, l4 = k-octet; tile col c = (j%32)*4 + gate)
// blockIdx == B_SZ+NG  : bias sum
__global__ void __launch_bounds__(192) prepass(const float* __restrict__ x,
                                               const float* __restrict__ h,
                                               const float* __restrict__ Wx,
                                               const float* __restrict__ Wh,
                                               const float* __restrict__ bx,
                                               const float* __restrict__ bh,
                                               _Float16* __restrict__ Aw,
                                               _Float16* __restrict__ Wf,
                                               float* __restrict__ bs) {
  const int t = threadIdx.x;
  const int bid = blockIdx.x;
  if (bid < B_SZ) {
    const int r = bid;
    float4 v;
    int col;
    if (t < 64) { col = t * 4;              v = *(const float4*)(x + (size_t)r * I_SZ + col); }
    else        { col = 256 + (t - 64) * 4; v = *(const float4*)(h + (size_t)r * H_SZ + (col - 256)); }
    half4v o = {(_Float16)v.x, (_Float16)v.y, (_Float16)v.z, (_Float16)v.w};
    *(half4v*)(Aw + (size_t)r * K_SZ + col) = o;
  } else if (bid < B_SZ + NG) {
    const int r = bid - B_SZ;            // Ww row = gate*512 + j
    const int g = r >> 9, j = r & 511;
    const int nb = j >> 5, jl = j & 31;
    const int cc = jl * 4 + g;           // tile col within 128-col block
    const int wc = cc >> 6, ni = (cc >> 4) & 3, l15 = cc & 15;
    const int k = t * 4;
    float4 v;
    if (t < 64) v = *(const float4*)(Wx + (size_t)r * I_SZ + k);
    else        v = *(const float4*)(Wh + (size_t)r * H_SZ + (k - 256));
    const int kb = k >> 6, ks = (k >> 5) & 1, l4 = (k >> 3) & 3, e = k & 7;
    const int f = (((nb * 2 + wc) * 12 + kb) * 2 + ks) * 4 + ni;
    half4v o = {(_Float16)v.x, (_Float16)v.y, (_Float16)v.z, (_Float16)v.w};
    *(half4v*)(Wf + (size_t)f * 512 + (l4 * 16 + l15) * 8 + e) = o;
  } else {
    for (int j = t; j < NG; j += 192) bs[j] = bx[j] + bh[j];
  }
}

// ---------------- main fused GEMM + LSTM epilogue ----------------
// 128x128 block tile, 4 waves 2x2, 16x16x32 f16 MFMA, BK=64.
// A: LDS double buffer (2x16KB), XOR-swizzled chunks, global_load_lds width 16,
//    ONE barrier per K-iter (prefetch issued right after barrier -> drain is free).
// W: no LDS — fragment-ordered global loads (L2-resident, coalesced dwordx4).
__global__ void __launch_bounds__(256) lstm_gemm(const _Float16* __restrict__ Aw,
                                                 const _Float16* __restrict__ Wf,
                                                 const float* __restrict__ bs,
                                                 const float* __restrict__ cIn,
                                                 float* __restrict__ outc,
                                                 float* __restrict__ outh) {
  __shared__ __align__(16) char smem[32768];

  const int t = threadIdx.x;
  const int lane = t & 63;
  const int wave = t >> 6;
  const int wr = wave >> 1, wc = wave & 1;
  const int l15 = lane & 15, l4 = lane >> 4;
  const int sw = l15 & 7;

  const int bid = blockIdx.x;
  const int nb = bid & 15, mb = bid >> 4;   // 16 consecutive blocks share the A panel
  const int j0 = nb * 32;
  const int m0 = mb * 128;

  // A staging: thread t -> row rA=t>>3 (of 32-row group q), chunk ct=t&7, XOR swizzle
  const int rA = t >> 3;
  const int colb = ((t & 7) ^ (rA & 7)) * 8;
  const size_t aBase = (size_t)(m0 + rA) * K_SZ + colb;

  // W fragment base for this (nb, wc): per (kb,ks,ni) offset (kb*8+ks*4+ni)*512
  const _Float16* wBase = Wf + (size_t)(nb * 2 + wc) * 96 * 512 + lane * 8;

  // init accumulators with bias
  f32x4 acc[4][4];
#pragma unroll
  for (int ni = 0; ni < 4; ++ni) {
    int tcol = wc * 64 + ni * 16 + l15;
    int gcol = (tcol & 3) * H_SZ + j0 + (tcol >> 2);
    float b = bs[gcol];
    f32x4 v = {b, b, b, b};
#pragma unroll
    for (int mi = 0; mi < 4; ++mi) acc[mi][ni] = v;
  }

  // prologue: stage kb=0 into buf0
#pragma unroll
  for (int q = 0; q < 4; ++q)
    gl2lds16(Aw + aBase + (size_t)q * 32 * K_SZ, smem + t * 16 + q * 4096);

  for (int kb = 0; kb < K_SZ / 64; ++kb) {
    __syncthreads();  // vmcnt(0) drain covers loads issued one full iter ago
    if (kb < K_SZ / 64 - 1) {
      char* ldsNext = smem + ((kb + 1) & 1) * 16384 + t * 16;
#pragma unroll
      for (int q = 0; q < 4; ++q)
        gl2lds16(Aw + aBase + (size_t)q * 32 * K_SZ + (size_t)(kb + 1) * 64,
                 ldsNext + q * 4096);
    }
    const _Float16* As = (const _Float16*)(smem + (kb & 1) * 16384);
#pragma unroll
    for (int ks = 0; ks < 2; ++ks) {
      half8 af[4], wf[4];
#pragma unroll
      for (int ni = 0; ni < 4; ++ni)
        wf[ni] = *(const half8*)(wBase + (size_t)(kb * 8 + ks * 4 + ni) * 512);
#pragma unroll
      for (int mi = 0; mi < 4; ++mi)
        af[mi] = *(const half8*)(As + (wr * 64 + mi * 16 + l15) * 64 + (((ks * 4 + l4) ^ sw) * 8));
#pragma unroll
      for (int mi = 0; mi < 4; ++mi)
#pragma unroll
        for (int ni = 0; ni < 4; ++ni)
          acc[mi][ni] = __builtin_amdgcn_mfma_f32_16x16x32_f16(af[mi], wf[ni], acc[mi][ni], 0, 0, 0);
    }
  }
  __syncthreads();  // K-loop reads done before epilogue reuses LDS

  // ---- epilogue: per-wave LDS transpose (stride 68 floats) ----
  float* T = (float*)(smem + wave * 8192);
#pragma unroll
  for (int mi = 0; mi < 4; ++mi) {
#pragma unroll
    for (int ni = 0; ni < 4; ++ni)
#pragma unroll
      for (int r = 0; r < 4; ++r)
        T[(l4 * 4 + r) * 68 + ni * 16 + l15] = acc[mi][ni][r];
#pragma unroll
    for (int orow = 0; orow < 4; ++orow) {
      int rloc = orow * 4 + l4;
      f32x4 gv = *(const f32x4*)(T + rloc * 68 + l15 * 4);
      int rowg = m0 + wr * 64 + mi * 16 + rloc;
      int jg = j0 + wc * 16 + l15;
      size_t off = (size_t)rowg * H_SZ + jg;
      float cv = cIn[off];
      float it = sigf(gv[0]);
      float ft = sigf(gv[1]);
      float ot = sigf(gv[2]);
      float tc = tanh_fast(gv[3]);
      float ct = ft * cv + it * tc;
      float ht = ot * tanh_fast(ct);
      outc[off] = ct;
      outh[off] = ht;
    }
  }
}

// ---------------- fallback (ws too small): plain fp32 ----------------
__global__ void __launch_bounds__(256) lstm_naive(const float* __restrict__ x,
                                                  const float* __restrict__ h,
                                                  const float* __restrict__ c,
                                                  const float* __restrict__ Wx,
                                                  const float* __restrict__ bx,
                                                  const float* __restrict__ Wh,
                                                  const float* __restrict__ bh,
                                                  float* __restrict__ outc,
                                                  float* __restrict__ outh) {
  int idx = blockIdx.x * 256 + threadIdx.x;
  int b = idx >> 9, j = idx & 511;
  float gi = bx[j] + bh[j];
  float gf = bx[H_SZ + j] + bh[H_SZ + j];
  float go = bx[2 * H_SZ + j] + bh[2 * H_SZ + j];
  float gc = bx[3 * H_SZ + j] + bh[3 * H_SZ + j];
  const float* xr = x + (size_t)b * I_SZ;
  for (int k = 0; k < I_SZ; ++k) {
    float xv = xr[k];
    gi += xv * Wx[(size_t)j * I_SZ + k];
    gf += xv * Wx[(size_t)(H_SZ + j) * I_SZ + k];
    go += xv * Wx[(size_t)(2 * H_SZ + j) * I_SZ + k];
    gc += xv * Wx[(size_t)(3 * H_SZ + j) * I_SZ + k];
  }
  const float* hr = h + (size_t)b * H_SZ;
  for (int k = 0; k < H_SZ; ++k) {
    float hv = hr[k];
    gi += hv * Wh[(size_t)j * H_SZ + k];
    gf += hv * Wh[(size_t)(H_SZ + j) * H_SZ + k];
    go += hv * Wh[(size_t)(2 * H_SZ + j) * H_SZ + k];
    gc += hv * Wh[(size_t)(3 * H_SZ + j) * H_SZ + k];
  }
  float it = sigf(gi), ft = sigf(gf), ot = sigf(go), tc = tanh_fast(gc);
  float ct = ft * c[idx] + it * tc;
  outc[idx] = ct;
  outh[idx] = ot * tanh_fast(ct);
}

extern "C" void kernel_launch(void* const* d_in, const int* in_sizes, int n_in,
                              void* d_out, int out_size, void* d_ws, size_t ws_size,
                              hipStream_t stream) {
  const float* x  = (const float*)d_in[0];
  const float* h  = (const float*)d_in[1];
  const float* c  = (const float*)d_in[2];
  const float* Wx = (const float*)d_in[3];
  const float* bx = (const float*)d_in[4];
  const float* Wh = (const float*)d_in[5];
  const float* bh = (const float*)d_in[6];
  float* outc = (float*)d_out;
  float* outh = outc + (size_t)B_SZ * H_SZ;

  const size_t szA = (size_t)B_SZ * K_SZ * sizeof(_Float16);
  const size_t szW = (size_t)NG * K_SZ * sizeof(_Float16);
  const size_t need = szA + szW + (size_t)NG * sizeof(float);

  if (ws_size < need) {
    lstm_naive<<<(B_SZ * H_SZ) / 256, 256, 0, stream>>>(x, h, c, Wx, bx, Wh, bh, outc, outh);
    return;
  }

  _Float16* Aw = (_Float16*)d_ws;
  _Float16* Wf = (_Float16*)((char*)d_ws + szA);
  float* bs = (float*)((char*)d_ws + szA + szW);

  prepass<<<B_SZ + NG + 1, 192, 0, stream>>>(x, h, Wx, Wh, bx, bh, Aw, Wf, bs);
  lstm_gemm<<<(B_SZ / 128) * (NG / 128), 256, 0, stream>>>(Aw, Wf, bs, c, outc, outh);
}